// Round 7
// baseline (111.460 us; speedup 1.0000x reference)
//
#include <hip/hip_runtime.h>

// ---------------------------------------------------------------------------
// Native Sparse Attention (B=2, H=8, S=2048, D=64)
// Tile = (bh, qt): 32 queries. 256 threads = 4 waves, wave owns 8 queries.
// 1024 blocks -> 4 independent blocks/CU (TLP for latency hiding).
// Block top-8: exact fp32 factorized (sum_q Q over the 64-query GROUP)·K̄,
// computed redundantly per-wave -> identical selection in both half-tiles.
// All attention branches: bf16 MFMA QK + bf16 MFMA PV.
// Staging buffers: [row][32 uints], XOR-swizzled (chunk ^= row&7) -> balanced
// banks on ds_read_b128. One raw s_barrier (lgkm-only) per stage; global
// prefetch loads stay in flight across it.
// ---------------------------------------------------------------------------

constexpr int SS   = 2048;
constexpr int DD   = 64;
constexpr int NBLK = 32;
constexpr int BS   = 64;
constexpr int SNB  = 8;
constexpr int KKEEP = 256;
constexpr float SCALE  = 0.125f;
constexpr float NEGINF = -1e30f;

#define DEV __device__ __forceinline__

typedef __attribute__((ext_vector_type(8))) short s8_t;   // 8 x bf16
typedef __attribute__((ext_vector_type(4))) float f4_t;   // MFMA C/D frag

union S8U { uint4 u; s8_t s; };

DEV s8_t as_s8(uint4 u) { S8U x; x.u = u; return x.s; }
DEV s8_t s8zero() { uint4 z = {0, 0, 0, 0}; return as_s8(z); }

DEV float readlane_f(float x, int l) {
  return __int_as_float(__builtin_amdgcn_readlane(__float_as_int(x), l));
}
DEV float wave_max(float x) {
#pragma unroll
  for (int o = 32; o > 0; o >>= 1) x = fmaxf(x, __shfl_xor(x, o, 64));
  return x;
}
DEV float wave_sum(float x) {
#pragma unroll
  for (int o = 32; o > 0; o >>= 1) x += __shfl_xor(x, o, 64);
  return x;
}
DEV unsigned cvt_pk(float lo, float hi) {
  unsigned d;
  asm("v_cvt_pk_bf16_f32 %0, %1, %2" : "=v"(d) : "v"(lo), "v"(hi));
  return d;
}
DEV f4_t mfma16(s8_t a, s8_t b, f4_t c) {
  return __builtin_amdgcn_mfma_f32_16x16x32_bf16(a, b, c, 0, 0, 0);
}
DEV void wave_fence() {
  asm volatile("s_waitcnt lgkmcnt(0)" ::: "memory");
  __builtin_amdgcn_sched_barrier(0);
}
// raw workgroup barrier, LDS-only fence: vmcnt NOT drained.
DEV void ldsbar() {
  asm volatile("s_waitcnt lgkmcnt(0)" ::: "memory");
  __builtin_amdgcn_sched_barrier(0);
  __builtin_amdgcn_s_barrier();
  __builtin_amdgcn_sched_barrier(0);
}

// swizzled uint index for [row][8 chunks of 4 uints] buffer
DEV int swz(int row, int chunk) { return row * 32 + (((chunk) ^ (row & 7)) << 2); }

// ---- staging loads/writes (256 threads) ----
DEV void loadK4(const float* __restrict__ src, int tid, float4 pf[4]) {
  const int r0 = tid >> 4, c4 = tid & 15;
#pragma unroll
  for (int m = 0; m < 4; ++m)
    pf[m] = *(const float4*)(src + (r0 + 16 * m) * DD + c4 * 4);
}
DEV void writeK4(unsigned* b, const float4 pf[4], int tid) {
  const int r0 = tid >> 4, c4 = tid & 15;
#pragma unroll
  for (int m = 0; m < 4; ++m) {
    const int row = r0 + 16 * m;
    const int a = swz(row, c4 >> 1) + (c4 & 1) * 2;
    b[a]     = cvt_pk(pf[m].x, pf[m].y);
    b[a + 1] = cvt_pk(pf[m].z, pf[m].w);
  }
}
// K̄ stage: rows 0..31 = block means, row 32 = k0, rows 33..63 = 0
DEV void loadKbar(const float* __restrict__ kbar, const float* __restrict__ k0,
                  int tid, float4 pf[4]) {
  const int r0 = tid >> 4, c4 = tid & 15;
  pf[0] = *(const float4*)(kbar + r0 * DD + c4 * 4);
  pf[1] = *(const float4*)(kbar + (r0 + 16) * DD + c4 * 4);
  pf[2] = *(const float4*)(k0 + c4 * 4);
}
DEV void writeKbar4(unsigned* b, const float4 pf[4], int tid) {
  const int r0 = tid >> 4, c4 = tid & 15;
  {
    const int a = swz(r0, c4 >> 1) + (c4 & 1) * 2;
    b[a] = cvt_pk(pf[0].x, pf[0].y); b[a + 1] = cvt_pk(pf[0].z, pf[0].w);
  }
  {
    const int a = swz(r0 + 16, c4 >> 1) + (c4 & 1) * 2;
    b[a] = cvt_pk(pf[1].x, pf[1].y); b[a + 1] = cvt_pk(pf[1].z, pf[1].w);
  }
  {
    const int a = swz(r0 + 32, c4 >> 1) + (c4 & 1) * 2;
    const unsigned u0 = (r0 == 0) ? cvt_pk(pf[2].x, pf[2].y) : 0u;
    const unsigned u1 = (r0 == 0) ? cvt_pk(pf[2].z, pf[2].w) : 0u;
    b[a] = u0; b[a + 1] = u1;
  }
  {
    const int a = swz(r0 + 48, c4 >> 1) + (c4 & 1) * 2;
    b[a] = 0u; b[a + 1] = 0u;
  }
}
DEV void loadV4(const float* __restrict__ src, int tid, float4 pf[4]) {
  const int tp = tid & 31, dg = tid >> 5;
  pf[0] = *(const float4*)(src + (2 * tp) * DD + dg * 8);
  pf[1] = *(const float4*)(src + (2 * tp) * DD + dg * 8 + 4);
  pf[2] = *(const float4*)(src + (2 * tp + 1) * DD + dg * 8);
  pf[3] = *(const float4*)(src + (2 * tp + 1) * DD + dg * 8 + 4);
}
// transposed: [dim][tok-pair uints]
DEV void writeV4(unsigned* b, const float4 pf[4], int tid) {
  const int tp = tid & 31, dg = tid >> 5;
  const float fa[8] = {pf[0].x, pf[0].y, pf[0].z, pf[0].w,
                       pf[1].x, pf[1].y, pf[1].z, pf[1].w};
  const float fb[8] = {pf[2].x, pf[2].y, pf[2].z, pf[2].w,
                       pf[3].x, pf[3].y, pf[3].z, pf[3].w};
#pragma unroll
  for (int i = 0; i < 8; ++i) {
    const int dim = dg * 8 + i;
    b[swz(dim, tp >> 2) + (tp & 3)] = cvt_pk(fa[i], fb[i]);
  }
}
// V̄ stage: tok-pairs 0..15 = means, pair 16 = (v0, 0), pairs 17..31 = 0
DEV void loadVbar(const float* __restrict__ vbar, const float* __restrict__ v0,
                  int tid, float4 pf[4]) {
  const int tp = tid & 31, dg = tid >> 5;
  if (tp < 16) {
    pf[0] = *(const float4*)(vbar + (2 * tp) * DD + dg * 8);
    pf[1] = *(const float4*)(vbar + (2 * tp) * DD + dg * 8 + 4);
    pf[2] = *(const float4*)(vbar + (2 * tp + 1) * DD + dg * 8);
    pf[3] = *(const float4*)(vbar + (2 * tp + 1) * DD + dg * 8 + 4);
  } else if (tp == 16) {
    pf[0] = *(const float4*)(v0 + dg * 8);
    pf[1] = *(const float4*)(v0 + dg * 8 + 4);
  }
}
DEV void writeVbar4(unsigned* b, const float4 pf[4], int tid) {
  const int tp = tid & 31, dg = tid >> 5;
  const float fa[8] = {pf[0].x, pf[0].y, pf[0].z, pf[0].w,
                       pf[1].x, pf[1].y, pf[1].z, pf[1].w};
  const float fb[8] = {pf[2].x, pf[2].y, pf[2].z, pf[2].w,
                       pf[3].x, pf[3].y, pf[3].z, pf[3].w};
#pragma unroll
  for (int i = 0; i < 8; ++i) {
    const int dim = dg * 8 + i;
    unsigned val = 0u;
    if (tp < 16)       val = cvt_pk(fa[i], fb[i]);
    else if (tp == 16) val = cvt_pk(fa[i], 0.f);
    b[swz(dim, tp >> 2) + (tp & 3)] = val;
  }
}

// QK / PV B-frag MFMA over swizzled buffer (row = token for K, dim for V^T)
DEV void qk8(const unsigned* b, const s8_t qA[2], int qi, int g, f4_t c[4]) {
#pragma unroll
  for (int t = 0; t < 4; ++t) {
    f4_t acc = {0.f, 0.f, 0.f, 0.f};
#pragma unroll
    for (int ks = 0; ks < 2; ++ks) {
      const s8_t B = as_s8(*(const uint4*)(b + swz(t * 16 + qi, 4 * ks + g)));
      acc = mfma16(qA[ks], B, acc);
    }
    c[t] = acc;
  }
}

// redistribute C frags (q-rows 0..7) -> per-lane raw[j] (lane = col)
DEV void redist(const f4_t c[4], float* scw, int lane, float raw[8]) {
  if (lane < 32) {
    const int g2 = lane >> 4, ci = lane & 15;
#pragma unroll
    for (int t = 0; t < 4; ++t)
#pragma unroll
      for (int r = 0; r < 4; ++r)
        scw[(g2 * 4 + r) * 68 + t * 16 + ci] = c[t][r];
  }
  wave_fence();
#pragma unroll
  for (int j = 0; j < 8; ++j) raw[j] = scw[j * 68 + lane];
}

// ---------------------------------------------------------------------------
__global__ __launch_bounds__(64) void nsa_means(const float* __restrict__ k,
                                                const float* __restrict__ v,
                                                float* __restrict__ kblk,
                                                float* __restrict__ vblk) {
  const int n = blockIdx.x, bh = blockIdx.y, d = threadIdx.x;
  const float* kb = k + ((size_t)bh * SS + (size_t)n * BS) * DD;
  const float* vb = v + ((size_t)bh * SS + (size_t)n * BS) * DD;
  float sk = 0.f, sv = 0.f;
  for (int t = 0; t < BS; ++t) { sk += kb[t * DD + d]; sv += vb[t * DD + d]; }
  kblk[((size_t)bh * NBLK + n) * DD + d] = sk * (1.f / 64.f);
  vblk[((size_t)bh * NBLK + n) * DD + d] = sv * (1.f / 64.f);
}

// ---------------------------------------------------------------------------
__global__ __launch_bounds__(256) void nsa_main(
    const float* __restrict__ qg, const float* __restrict__ kg,
    const float* __restrict__ vg, const float* __restrict__ kblk,
    const float* __restrict__ vblk, float* __restrict__ outg) {
  const int qt   = blockIdx.x;        // 0..63 : 32-query tile
  const int bh   = blockIdx.y;
  const int tid  = threadIdx.x;       // 0..255
  const int w    = tid >> 6;          // 0..3
  const int lane = tid & 63;
  const int gg   = qt >> 1;           // reference 64-query group index
  const int q0   = qt * 32;
  const size_t base = (size_t)bh * SS * DD;

  __shared__ __align__(16) unsigned buf_s[2][64 * 32];   // 16384 B
  __shared__ __align__(16) float sc_f[4][8 * 68];        // 8704 B per-wave
  __shared__ float partial_s[4][64];                     // 1024 B

  float* scw = sc_f[w];
  unsigned short* scwu = (unsigned short*)scw;
  const int qi = lane & 15, g = lane >> 4;
  const int qc = (qi < 8) ? qi : 0;
  const float* kbar = kblk + (size_t)bh * NBLK * DD;
  const float* vbar = vblk + (size_t)bh * NBLK * DD;

  // ---- prologue: group Q-row partial sums (wave w: rows gg*64+16w..+15) ----
  {
    const float* qrow = qg + base + (size_t)(gg * 64 + w * 16) * DD + lane;
    float qs = 0.f;
#pragma unroll
    for (int r = 0; r < 16; ++r) qs += qrow[r * DD];
    partial_s[w][lane] = qs;
  }
  // qA frags for this wave's 8 queries
  s8_t qA[2];
  {
    const float* qrow = qg + base + (size_t)(q0 + w * 8 + qc) * DD;
#pragma unroll
    for (int ks = 0; ks < 2; ++ks) {
      const float4 a = *(const float4*)(qrow + ks * 32 + g * 8);
      const float4 b = *(const float4*)(qrow + ks * 32 + g * 8 + 4);
      uint4 uu = {cvt_pk(a.x, a.y), cvt_pk(a.z, a.w),
                  cvt_pk(b.x, b.y), cvt_pk(b.z, b.w)};
      qA[ks] = (qi < 8) ? as_s8(uu) : s8zero();
    }
  }
  float4 pf[4];
  loadKbar(kbar, kg + base, tid, pf);
  ldsbar();   // publish partial_s (prefetch loads survive)

  // ---- per-wave redundant exact block scores + top-8 (per 64-group) ----
  int selreg[SNB];
  {
    float qm = 0.f;
#pragma unroll
    for (int ww = 0; ww < 4; ++ww) qm += partial_s[ww][lane];
    scw[lane] = qm;   // unnormalized group mean (positive scale: rank-safe)
    wave_fence();
    const int n2 = lane & 31, half = lane >> 5;
    const float* krow = kbar + n2 * DD + half * 32;
    float p = 0.f;
#pragma unroll
    for (int dd = 0; dd < 32; ++dd) p = fmaf(scw[half * 32 + dd], krow[dd], p);
    p += __shfl_xor(p, 32, 64);
    float s = (lane < 32) ? ((n2 <= gg) ? p : NEGINF) : -3.4e38f;
    const int bi = lane;
    for (int t = 0; t < SNB; ++t) {
      float bs = s; int bb = bi;
#pragma unroll
      for (int o = 32; o > 0; o >>= 1) {
        const float os = __shfl_xor(bs, o, 64);
        const int   ob = __shfl_xor(bb, o, 64);
        if (os > bs || (os == bs && ob < bb)) { bs = os; bb = ob; }
      }
      selreg[t] = bb;
      if (bi == bb) s = -3.4e38f;
    }
  }

  // ============ K phase: stage 0 = K̄(+k0), 1..8 sel, 9..11 win ============
  unsigned cPp[4];
  float l192[8];
  // --- stage 0 ---
  writeKbar4(buf_s[0], pf, tid);
  loadK4(kg + base + (size_t)selreg[0] * BS * DD, tid, pf);
  ldsbar();
  {
    f4_t c[4];
    qk8(buf_s[0], qA, qi, g, c);
    float raw[8];
    redist(c, scw, lane, raw);
    float cPf[8];
#pragma unroll
    for (int j = 0; j < 8; ++j) {
      l192[j] = readlane_f(raw[j], 32) * SCALE;
      const bool valid = (lane < 32) && (lane <= gg);
      const float l = valid ? raw[j] * SCALE : NEGINF;
      const float m = wave_max(l);
      const float e = valid ? __expf(l - m) : 0.f;
      const float ssum = wave_sum(e);
      cPf[j] = e / ssum;
    }
#pragma unroll
    for (int ip = 0; ip < 4; ++ip) cPp[ip] = cvt_pk(cPf[2 * ip], cPf[2 * ip + 1]);
  }

  // --- stages 1..8: sel QK ---
  float L[8][SNB];
#pragma unroll
  for (int sbi = 0; sbi < SNB; ++sbi) {
    unsigned* buf = buf_s[(1 + sbi) & 1];
    writeK4(buf, pf, tid);
    {
      const int nb = (sbi < SNB - 1) ? selreg[sbi + 1] : ((gg > 2) ? gg - 2 : 0);
      loadK4(kg + base + (size_t)nb * BS * DD, tid, pf);
    }
    ldsbar();
    f4_t c[4];
    qk8(buf, qA, qi, g, c);
    float raw[8];
    redist(c, scw, lane, raw);
    const int tok = selreg[sbi] * BS + lane;
#pragma unroll
    for (int j = 0; j < 8; ++j) {
      const int pos = q0 + w * 8 + j;
      L[j][sbi] = (tok <= pos) ? raw[j] * SCALE : NEGINF;
    }
  }

  // ---- threshold (float-window) + sel softmax -> packed bf16 ----
  unsigned Lp[8][4];
#pragma unroll
  for (int j = 0; j < 8; ++j) {
    float m = L[j][0];
#pragma unroll
    for (int i = 1; i < SNB; ++i) m = fmaxf(m, L[j][i]);
    m = wave_max(m);
    float lo = m - 20.f, hi = m;
    int c0 = 0;
#pragma unroll
    for (int i = 0; i < SNB; ++i) c0 += __popcll(__ballot(L[j][i] >= lo));
    if (c0 >= KKEEP) {
      for (int it = 0; it < 16; ++it) {
        const float mid = 0.5f * (lo + hi);
        int cc = 0;
#pragma unroll
        for (int i = 0; i < SNB; ++i) cc += __popcll(__ballot(L[j][i] >= mid));
        if (cc >= KKEEP) lo = mid; else hi = mid;
      }
    }
    const float thr = lo;
    float s = 0.f;
#pragma unroll
    for (int i = 0; i < SNB; ++i) {
      const float e = (L[j][i] >= thr) ? __expf(L[j][i] - m) : 0.f;
      L[j][i] = e; s += e;
    }
    s = wave_sum(s);
    const float inv = 1.f / s;
#pragma unroll
    for (int ip = 0; ip < 4; ++ip)
      Lp[j][ip] = cvt_pk(L[j][2 * ip] * inv, L[j][2 * ip + 1] * inv);
  }

  // --- stages 9..11: win QK (blocks gg-2..gg, clamped loads, masked) ---
  float Lw[8][3];
#pragma unroll
  for (int wi = 0; wi < 3; ++wi) {
    const int wb = gg - 2 + wi;
    unsigned* buf = buf_s[(9 + wi) & 1];
    writeK4(buf, pf, tid);
    if (wi < 2) {
      const int nb = (gg - 1 + wi > 0) ? gg - 1 + wi : 0;
      loadK4(kg + base + (size_t)nb * BS * DD, tid, pf);
    } else {
      loadVbar(vbar, vg + base, tid, pf);   // prefetch V̄ stage
    }
    ldsbar();
    f4_t c[4];
    qk8(buf, qA, qi, g, c);
    float raw[8];
    redist(c, scw, lane, raw);
    const int tok = wb * BS + lane;
#pragma unroll
    for (int j = 0; j < 8; ++j) {
      const int pos = q0 + w * 8 + j;
      const bool valid = (wb >= 0) && (tok <= pos) && ((pos - tok < 128) || (tok == 0));
      Lw[j][wi] = valid ? raw[j] * SCALE : NEGINF;
    }
  }

  // ---- win softmax (global-token column l192 when gg >= 3) ----
  unsigned Lwp[8][2];
  float p192[8];
#pragma unroll
  for (int j = 0; j < 8; ++j) {
    const float l1 = (gg >= 3) ? l192[j] : NEGINF;
    float m = fmaxf(fmaxf(Lw[j][0], Lw[j][1]), Lw[j][2]);
    m = wave_max(m);
    m = fmaxf(m, l1);
    const float e0 = __expf(Lw[j][0] - m);
    const float e1 = __expf(Lw[j][1] - m);
    const float e2 = __expf(Lw[j][2] - m);
    float s = wave_sum(e0 + e1 + e2);
    const float e192 = (gg >= 3) ? __expf(l1 - m) : 0.f;
    s += e192;
    const float inv = 1.f / s;
    Lwp[j][0] = cvt_pk(e0 * inv, e1 * inv);
    Lwp[j][1] = cvt_pk(e2 * inv, 0.f);
    p192[j] = e192 * inv;
  }

  // ============ V phase: stage 12 = V̄(+v0), 13..20 sel, 21..23 win ========
  f4_t Of[4];
#pragma unroll
  for (int t = 0; t < 4; ++t) Of[t] = (f4_t){0.f, 0.f, 0.f, 0.f};

  // --- stage 12: V̄ ---
  writeVbar4(buf_s[0], pf, tid);
#pragma unroll
  for (int j = 0; j < 8; ++j) {
    const unsigned uu = cPp[j >> 1];
    unsigned short pv = (unsigned short)((j & 1) ? (uu >> 16) : (uu & 0xffffu));
    if (lane == 32) pv = (unsigned short)(cvt_pk(p192[j], 0.f) & 0xffffu);
    else if (lane > 32) pv = 0;
    scwu[j * 136 + lane] = pv;
  }
  loadV4(vg + base + (size_t)selreg[0] * BS * DD, tid, pf);
  ldsbar();
#pragma unroll
  for (int ks = 0; ks < 2; ++ks) {
    s8_t Pa = as_s8(*(const uint4*)(scwu + qc * 136 + ks * 32 + g * 8));
    if (qi >= 8) Pa = s8zero();
#pragma unroll
    for (int t = 0; t < 4; ++t) {
      const s8_t Vt = as_s8(*(const uint4*)(buf_s[0] + swz(t * 16 + qi, 4 * ks + g)));
      Of[t] = mfma16(Pa, Vt, Of[t]);
    }
  }

  // --- stages 13..20: sel PV ---
#pragma unroll
  for (int sbi = 0; sbi < SNB; ++sbi) {
    unsigned* buf = buf_s[(13 + sbi) & 1];
    writeV4(buf, pf, tid);
#pragma unroll
    for (int j = 0; j < 8; ++j) {
      const unsigned uu = Lp[j][sbi >> 1];
      scwu[j * 136 + lane] = (unsigned short)((sbi & 1) ? (uu >> 16) : (uu & 0xffffu));
    }
    {
      const int nb = (sbi < SNB - 1) ? selreg[sbi + 1] : ((gg > 2) ? gg - 2 : 0);
      loadV4(vg + base + (size_t)nb * BS * DD, tid, pf);
    }
    ldsbar();
#pragma unroll
    for (int ks = 0; ks < 2; ++ks) {
      s8_t Pa = as_s8(*(const uint4*)(scwu + qc * 136 + ks * 32 + g * 8));
      if (qi >= 8) Pa = s8zero();
#pragma unroll
      for (int t = 0; t < 4; ++t) {
        const s8_t Vt = as_s8(*(const uint4*)(buf + swz(t * 16 + qi, 4 * ks + g)));
        Of[t] = mfma16(Pa, Vt, Of[t]);
      }
    }
  }

  // --- stages 21..23: win PV ---
#pragma unroll
  for (int wi = 0; wi < 3; ++wi) {
    unsigned* buf = buf_s[(21 + wi) & 1];
    writeV4(buf, pf, tid);
#pragma unroll
    for (int j = 0; j < 8; ++j) {
      const unsigned uu = Lwp[j][wi >> 1];
      scwu[j * 136 + lane] = (unsigned short)((wi & 1) ? (uu >> 16) : (uu & 0xffffu));
    }
    if (wi < 2) {
      const int nb = (gg - 1 + wi > 0) ? gg - 1 + wi : 0;
      loadV4(vg + base + (size_t)nb * BS * DD, tid, pf);
    }
    ldsbar();
#pragma unroll
    for (int ks = 0; ks < 2; ++ks) {
      s8_t Pa = as_s8(*(const uint4*)(scwu + qc * 136 + ks * 32 + g * 8));
      if (qi >= 8) Pa = s8zero();
#pragma unroll
      for (int t = 0; t < 4; ++t) {
        const s8_t Vt = as_s8(*(const uint4*)(buf + swz(t * 16 + qi, 4 * ks + g)));
        Of[t] = mfma16(Pa, Vt, Of[t]);
      }
    }
  }

  // ---- epilogue: Of -> lane=dim, store (cmp+sel+win+global)/3 ----
  float ofin[8];
  redist(Of, scw, lane, ofin);
#pragma unroll
  for (int j = 0; j < 8; ++j)
    outg[base + (size_t)(q0 + w * 8 + j) * DD + lane] = ofin[j] * (1.f / 3.f);
}

// ---------------------------------------------------------------------------
extern "C" void kernel_launch(void* const* d_in, const int* in_sizes, int n_in,
                              void* d_out, int out_size, void* d_ws, size_t ws_size,
                              hipStream_t stream) {
  (void)in_sizes; (void)n_in; (void)out_size; (void)ws_size;
  const float* q = (const float*)d_in[0];
  const float* k = (const float*)d_in[1];
  const float* v = (const float*)d_in[2];
  float* out = (float*)d_out;
  float* wsf = (float*)d_ws;
  float* kblk = wsf;
  float* vblk = wsf + 16 * NBLK * DD;

  dim3 g1(NBLK, 16);
  nsa_means<<<g1, 64, 0, stream>>>(k, v, kblk, vblk);
  dim3 g2(64, 16);
  nsa_main<<<g2, 256, 0, stream>>>(q, k, v, kblk, vblk, out);
}